// Round 9
// baseline (2093.143 us; speedup 1.0000x reference)
//
#include <hip/hip_runtime.h>
#include <stdint.h>

#define NB 128
#define NT 2048
#define NI 128
#define NH 1024
#define NO 128

typedef float f32x4 __attribute__((ext_vector_type(4)));
typedef float f32x16 __attribute__((ext_vector_type(16)));

// ---------------------------------------------------------------------------
// W2P: pair-transpose W2 [O][H] -> W2P [H][64] of float2 {W2[j][k], W2[j+64][k]}
// ---------------------------------------------------------------------------
__global__ __launch_bounds__(256) void w2p_kernel(
    const float* __restrict__ W2, float2* __restrict__ W2P)
{
    const int idx = blockIdx.x * 256 + threadIdx.x;  // 0..65535
    const int k = idx >> 6;                          // 0..1023
    const int j = idx & 63;                          // 0..63
    W2P[idx] = make_float2(W2[(size_t)j * NH + k], W2[(size_t)(j + 64) * NH + k]);
}

// Pin one weight quad in a NAMED f32x4 (asm def: non-rematerializable).
#define WLQ(V, OFF)                                                       \
    asm volatile("global_load_dwordx4 %0, %1, off offset:" #OFF          \
                 : "=v"(V) : "v"(wp))

// 4 FMAs: one weight quad against 4 consecutive SGPR x components.
// acc index = k&3, k ascending (same grouping as R0/R5 -> absmax 0.0).
#define Q4(WQ, XV, J)                                                     \
    do {                                                                  \
        a0 = fmaf(WQ.x, (XV)[(J) + 0], a0);                               \
        a1 = fmaf(WQ.y, (XV)[(J) + 1], a1);                               \
        a2 = fmaf(WQ.z, (XV)[(J) + 2], a2);                               \
        a3 = fmaf(WQ.w, (XV)[(J) + 3], a3);                               \
    } while (0)

// ---------------------------------------------------------------------------
// Phase A: fused GEMM1 + LIF1, k-quarter split.
// grid = 2048 (128 b x 16 hgroups of 64 h), block = 256 = 4 waves = 4
// k-quarters (wave kq covers k = kq*32..+31) of the SAME 64 h (lane = h).
// Per wave: 8 NAMED pinned weight quads (32 VGPR - half of R5's failed tuple
// pressure), x quarter via 2x s_load_dwordx16 (32 SGPR, R5-proven SMEM path),
// 32 FMA/t. Quarters combine via 2-slot-parity LDS (1 barrier/t, R1-proven).
// Wave kq0 runs LIF + ballot + spike store.
// ---------------------------------------------------------------------------
__global__ __launch_bounds__(256, 4) void snn_phaseA(
    const float* __restrict__ x, const float* __restrict__ W1,
    const float* __restrict__ b1, uint64_t* __restrict__ s1bits)
{
    const int b = blockIdx.x >> 4;      // 0..127
    const int hg = blockIdx.x & 15;     // 0..15
    const int kq = __builtin_amdgcn_readfirstlane(threadIdx.x >> 6);  // 0..3
    const int lane = threadIdx.x & 63;
    const int h = hg * 64 + lane;

    f32x4 wq0, wq1, wq2, wq3, wq4, wq5, wq6, wq7;
    const float* wp = W1 + (size_t)h * NI + kq * 32;
    WLQ(wq0, 0);  WLQ(wq1, 16); WLQ(wq2, 32);  WLQ(wq3, 48);
    WLQ(wq4, 64); WLQ(wq5, 80); WLQ(wq6, 96);  WLQ(wq7, 112);
    asm volatile("s_waitcnt vmcnt(0)"
                 : "+v"(wq0), "+v"(wq1), "+v"(wq2), "+v"(wq3),
                   "+v"(wq4), "+v"(wq5), "+v"(wq6), "+v"(wq7)
                 :
                 : "memory");
    __builtin_amdgcn_sched_barrier(0);

    const float bias = b1[h];
    __shared__ float red[2][3][64];

    const float* __restrict__ xb = x + (size_t)b * NT * NI + kq * 32;
    uint64_t* s1w = s1bits + (size_t)b * (NH / 64) + hg;

    float v = 0.0f;
#pragma unroll 1
    for (int t = 0; t < NT; ++t) {
        const float* xr = xb + (size_t)t * NI;  // wave-uniform -> SGPR pair
        f32x16 xlo, xhi;
        asm volatile("s_load_dwordx16 %0, %1, 0x0"  : "=s"(xlo) : "s"(xr));
        asm volatile("s_load_dwordx16 %0, %1, 0x40" : "=s"(xhi) : "s"(xr));
        asm volatile("s_waitcnt lgkmcnt(0)" : "+s"(xlo), "+s"(xhi));
        __builtin_amdgcn_sched_barrier(0);

        float a0 = 0.f, a1 = 0.f, a2 = 0.f, a3 = 0.f;
        Q4(wq0, xlo, 0);  Q4(wq1, xlo, 4);  Q4(wq2, xlo, 8);  Q4(wq3, xlo, 12);
        Q4(wq4, xhi, 0);  Q4(wq5, xhi, 4);  Q4(wq6, xhi, 8);  Q4(wq7, xhi, 12);
        const float partial = (a0 + a1) + (a2 + a3);

        if (kq) red[t & 1][kq - 1][lane] = partial;
        __syncthreads();
        if (!kq) {
            const float r0 = red[t & 1][0][lane];
            const float r1 = red[t & 1][1][lane];
            const float r2 = red[t & 1][2][lane];
            const float h1 = ((partial + r0) + (r1 + r2)) + bias;
            v = fmaf(h1 - v, 0.5f, v);  // v += (h1 - v)/tau, tau = 2
            const bool sp = (v >= 1.0f);
            v = sp ? 0.0f : v;
            const unsigned long long m = __ballot(sp);
            if (lane == 0) *s1w = (uint64_t)m;
        }
        s1w += NB * (NH / 64);
        // slot red[t&1] is next written at t+2, after barrier(t+1): safe.
    }
}

// ---------------------------------------------------------------------------
// Phase B: sparse GEMM2. One wave per m = t*128+b row; lane covers o = lane
// and o+64. Scalar ff1 loop over 16 mask words; per active k one coalesced
// dwordx2 of W2P[k]. Sparse sum (ascending k) == dense sum exactly.
// ---------------------------------------------------------------------------
__global__ __launch_bounds__(256, 4) void snn_phaseB(
    const uint64_t* __restrict__ s1bits, const float2* __restrict__ W2P,
    float* __restrict__ h2)
{
    const int wv = threadIdx.x >> 6;
    const int lane = threadIdx.x & 63;
    const size_t m = (size_t)blockIdx.x * 4 + wv;  // 0..262143

    const uint64_t* __restrict__ sb = s1bits + m * (NH / 64);
    float a0 = 0.f, a1 = 0.f;

#pragma unroll 1
    for (int wd = 0; wd < NH / 64; ++wd) {
        const uint64_t m64 = sb[wd];
        const uint32_t mlo = (uint32_t)__builtin_amdgcn_readfirstlane((int)(uint32_t)m64);
        const uint32_t mhi = (uint32_t)__builtin_amdgcn_readfirstlane((int)(uint32_t)(m64 >> 32));
        uint64_t msk = ((uint64_t)mhi << 32) | mlo;
        while (msk) {
            const int i = __builtin_ctzll(msk);
            msk &= (msk - 1);
            const size_t k = ((size_t)wd << 6) + i;
            const float2 ww = W2P[k * 64 + lane];
            a0 += ww.x;
            a1 += ww.y;
        }
    }
    h2[m * NO + lane] = a0;
    h2[m * NO + 64 + lane] = a1;
}

// ---------------------------------------------------------------------------
// Phase D: LIF2 scan + decision-window count. 256 blocks of 64 threads,
// unroll 16 for deep load pipelining; lanes <-> consecutive o (coalesced).
// ---------------------------------------------------------------------------
__global__ __launch_bounds__(64) void snn_phaseD(
    const float* __restrict__ h2, const float* __restrict__ b2,
    float* __restrict__ out)
{
    const int idx = blockIdx.x * 64 + threadIdx.x;  // 0..16383
    const int b = idx >> 7;
    const int o = idx & 127;
    const float bias = b2[o];

    const float* __restrict__ p = h2 + (size_t)b * NO + o;
    float v = 0.f, c = 0.f;
#pragma unroll 16
    for (int t = 0; t < NT; ++t) {
        const float hh = p[(size_t)t * NB * NO] + bias;
        v = fmaf(hh - v, 0.5f, v);
        const bool s = (v >= 1.0f);
        v = s ? 0.f : v;
        if (t >= NT / 2) c += s ? 1.f : 0.f;
    }
    out[idx] = c;
}

extern "C" void kernel_launch(void* const* d_in, const int* in_sizes, int n_in,
                              void* d_out, int out_size, void* d_ws,
                              size_t ws_size, hipStream_t stream)
{
    const float* x  = (const float*)d_in[0];
    const float* W1 = (const float*)d_in[1];
    const float* b1 = (const float*)d_in[2];
    const float* W2 = (const float*)d_in[3];
    const float* b2 = (const float*)d_in[4];
    float* out = (float*)d_out;

    // ws layout: [s1bits 33.55 MB][W2P 0.52 MB][h2 134.2 MB]
    uint8_t* ws = (uint8_t*)d_ws;
    uint64_t* s1bits = (uint64_t*)ws;
    float2* W2P = (float2*)(ws + (size_t)NT * NB * (NH / 64) * 8);
    float* h2 = (float*)(ws + (size_t)NT * NB * (NH / 64) * 8 +
                         (size_t)NH * 64 * sizeof(float2));

    w2p_kernel<<<dim3((NH * 64) / 256), dim3(256), 0, stream>>>(W2, W2P);
    snn_phaseA<<<dim3(NB * 16), dim3(256), 0, stream>>>(x, W1, b1, s1bits);
    snn_phaseB<<<dim3((NT * NB) / 4), dim3(256), 0, stream>>>(s1bits, W2P, h2);
    snn_phaseD<<<dim3(256), dim3(64), 0, stream>>>(h2, b2, out);
}